// Round 10
// baseline (83.358 us; speedup 1.0000x reference)
//
#include <hip/hip_runtime.h>
#include <math.h>

// TripletLoss semi-hard mining, N=512, D=512, C=64.
// v10: ONE dispatch. v9's verified triangle-tile distance phase; the 16
// diagonal blocks additionally mine their 32-row stripe (v4-verified
// semantics) after polling Dm with data-as-flag readiness:
//   - d_ws is poisoned 0xAAAAAAAA (sign bit SET) every call;
//   - every value we write (distances, losses, counts+1) has sign bit CLEAR;
//   - all cross-block traffic uses relaxed AGENT-scope atomics (MALL-coherent,
//     no L2 writeback/invalidate fences — v5 showed those cost ~30 us).
// 16 (loss, cnt+1) slots, no RMW, no init; block (15,15) polls + finalizes.
// For each ordered positive pair (j,a):
//   neg = min{ d[j][k] : lbl[k]!=lbl[j], d[j][k] > d[j][a] }
//         else max{ d[j][k] : lbl[k]!=lbl[j] } (0 if none)
//   loss += max(0, MARGIN + d[j][a] - neg);  out = loss / (numpos + 1e-8)

#define NN 512
#define MARGIN_F 0.2f
#define LK 528                    // LDS row stride in shorts

typedef __attribute__((ext_vector_type(8))) short bf16x8;
typedef __attribute__((ext_vector_type(4))) float f32x4;

__device__ __forceinline__ unsigned short f2bf(float x){
    unsigned u = __float_as_uint(x);
    return (unsigned short)((u + 0x7FFFu + ((u >> 16) & 1u)) >> 16);   // RNE
}
__device__ __forceinline__ float bf2f(unsigned short h){
    return __uint_as_float(((unsigned)h) << 16);
}
__device__ __forceinline__ void dm_store(float* p, float v){
    __hip_atomic_store(p, v, __ATOMIC_RELAXED, __HIP_MEMORY_SCOPE_AGENT);
}

// LDS byte offsets (tile phase)
#define SH_OFF   0                 // 4*32*528*2 = 135168
#define SNI_OFF  135168            // 32 f32
#define SNJ_OFF  135296            // 32 f32
#define SCR_OFF  135424            // 4*64*16 = 4096 (K-half partials)
#define TRP_OFF  139520            // 4 * 16*17*4 = 4352 (per-wave transpose)
#define SM_BYTES 143872
// mining-phase overlay (diagonal blocks only, after __syncthreads)
#define OV_SLBL  0                 // 512 i32
#define OV_DROW  2048              // 8*512 f32
#define OV_PLIST 18432             // 8*128 u16
#define OV_PCNT  20480             // 8 i32
#define OV_WL    20544             // 8 f32
#define OV_WC    20576             // 8 i32

__global__ __launch_bounds__(512) void k_all(
    const int* __restrict__ labels,
    const float* __restrict__ emb,
    float* __restrict__ Dm,
    int* __restrict__ ctrl,        // [0..15] loss f32 slots, [16..31] cnt+1 slots
    float* __restrict__ out)
{
    __shared__ __align__(16) char sm[SM_BYTES];
    short* sh  = (short*)(sm + SH_OFF);           // [4][32][LK] Ihi/Ilo/Jhi/Jlo
    float* snI = (float*)(sm + SNI_OFF);
    float* snJ = (float*)(sm + SNJ_OFF);
    f32x4* scr = (f32x4*)(sm + SCR_OFF);          // [4][64]
    float* trp = (float*)(sm + TRP_OFF);          // [4][16*17]

    const int tid  = threadIdx.x;
    const int wave = tid >> 6, lane = tid & 63;

    // triangle map: blockIdx.x in [0,136) -> (bi,bj), bi<=bj
    int t = blockIdx.x, bi = 0;
    #pragma unroll
    for (int r = 0; r < 16; ++r) {
        const int rowlen = 16 - r;
        if (t < rowlen) { bi = r; break; }
        t -= rowlen;
    }
    const int bj = bi + t;

    // ---- staging: 64 rows (32 I + 32 J) fp32 -> bf16 hi/lo + norms ----
    {
        const int row = tid >> 3;                 // 0..63
        const int s8  = tid & 7;
        const int isJ = row >> 5;                 // 0:I 1:J
        const int rl  = row & 31;
        const int grow = (isJ ? bj : bi) * 32 + rl;
        const int bhi = (isJ << 1), blo = bhi + 1;
        const float4* Ep = (const float4*)emb;    // 128 float4 per row
        float ss = 0.f;
        #pragma unroll
        for (int i = 0; i < 16; ++i) {
            const int c4 = s8 + (i << 3);         // 0..127
            const float4 v = Ep[(size_t)grow * 128 + c4];
            ss = fmaf(v.x, v.x, ss); ss = fmaf(v.y, v.y, ss);
            ss = fmaf(v.z, v.z, ss); ss = fmaf(v.w, v.w, ss);
            ushort4 h, l;
            h.x = f2bf(v.x); l.x = f2bf(v.x - bf2f(h.x));
            h.y = f2bf(v.y); l.y = f2bf(v.y - bf2f(h.y));
            h.z = f2bf(v.z); l.z = f2bf(v.z - bf2f(h.z));
            h.w = f2bf(v.w); l.w = f2bf(v.w - bf2f(h.w));
            *(ushort4*)(&sh[(bhi * 32 + rl) * LK + (c4 << 2)]) = h;
            *(ushort4*)(&sh[(blo * 32 + rl) * LK + (c4 << 2)]) = l;
        }
        ss += __shfl_xor(ss, 1, 64);
        ss += __shfl_xor(ss, 2, 64);
        ss += __shfl_xor(ss, 4, 64);
        if (s8 == 0) { if (isJ) snJ[rl] = ss; else snI[rl] = ss; }
    }
    __syncthreads();

    // ---- MFMA: quad = quadrant, khalf = K half ----
    const int quad = wave & 3, khalf = wave >> 2;
    const int rowb = (quad >> 1) << 4, colb = (quad & 1) << 4;
    const int fr = lane & 15;
    const int q4 = lane >> 4;                     // 0..3
    const int k0 = q4 << 3;
    f32x4 acc = {0.f, 0.f, 0.f, 0.f};
    #pragma unroll
    for (int t8 = 0; t8 < 8; ++t8) {
        const int k = k0 + (((khalf << 3) + t8) << 5);
        const bf16x8 ahi = *(const bf16x8*)(&sh[(0 * 32 + rowb + fr) * LK + k]);
        const bf16x8 alo = *(const bf16x8*)(&sh[(1 * 32 + rowb + fr) * LK + k]);
        const bf16x8 bhi = *(const bf16x8*)(&sh[(2 * 32 + colb + fr) * LK + k]);
        const bf16x8 blo = *(const bf16x8*)(&sh[(3 * 32 + colb + fr) * LK + k]);
        acc = __builtin_amdgcn_mfma_f32_16x16x32_bf16(ahi, bhi, acc, 0, 0, 0);
        acc = __builtin_amdgcn_mfma_f32_16x16x32_bf16(ahi, blo, acc, 0, 0, 0);
        acc = __builtin_amdgcn_mfma_f32_16x16x32_bf16(alo, bhi, acc, 0, 0, 0);
    }
    if (khalf == 1) scr[quad * 64 + lane] = acc;
    __syncthreads();
    if (khalf == 0) {
        const f32x4 other = scr[quad * 64 + lane];
        acc[0] += other[0]; acc[1] += other[1];
        acc[2] += other[2]; acc[3] += other[3];
        // C/D layout col=lane&15, row=(lane>>4)*4+reg (m89-verified)
        const int colg = bj * 32 + colb + fr;
        const float sc = snJ[colb + fr];
        const int rl0 = rowb + (q4 << 2);
        float dv[4];
        #pragma unroll
        for (int reg = 0; reg < 4; ++reg) {
            const int rl = rl0 + reg;
            const float d2 = snI[rl] + sc - 2.f * acc[reg];
            dv[reg] = sqrtf(fmaxf(d2, 0.f));
            dm_store(&Dm[(size_t)(bi * 32 + rl) * NN + colg], dv[reg]);
        }
        // mirror tile via per-wave 16x17 transpose (intra-wave LDS only)
        float* T = trp + quad * (16 * 17);
        #pragma unroll
        for (int reg = 0; reg < 4; ++reg)
            T[fr * 17 + (q4 << 2) + reg] = dv[reg];   // T[col][row] = d(row,col)
        #pragma unroll
        for (int reg = 0; reg < 4; ++reg) {
            const float m = T[((q4 << 2) + reg) * 17 + fr];   // d(fr, 4q+reg)
            const int mrow = bj * 32 + colb + (q4 << 2) + reg;
            const int mcol = bi * 32 + rowb + fr;
            dm_store(&Dm[(size_t)mrow * NN + mcol], m);
        }
    }
    __syncthreads();                  // tile phase done; LDS free for overlay
    if (bi != bj) return;             // only the 16 diagonal blocks mine

    // ---- mining overlay ----
    int*   slbl  = (int*)(sm + OV_SLBL);
    float* drow  = (float*)(sm + OV_DROW);
    unsigned short* plist = (unsigned short*)(sm + OV_PLIST);
    int*   pcnt  = (int*)(sm + OV_PCNT);
    float* wl    = (float*)(sm + OV_WL);
    int*   wc    = (int*)(sm + OV_WC);

    slbl[tid] = labels[tid];
    __syncthreads();

    int lb[8];
    #pragma unroll
    for (int m = 0; m < 8; ++m) lb[m] = slbl[lane * 8 + m];

    float bl = 0.f; unsigned bc = 0;
    for (int rr = 0; rr < 4; ++rr) {            // 8 waves x 4 rows = 32 rows
        const int j = bi * 32 + (wave << 2) + rr;
        const unsigned* rowp = (const unsigned*)(Dm + (size_t)j * NN) + lane * 8;
        float d[8];
        // poll: poison 0xAAAAAAAA has sign bit set; all distances are >= 0
        for (;;) {
            bool rdy = true;
            #pragma unroll
            for (int m = 0; m < 8; ++m) {
                const unsigned w = __hip_atomic_load(rowp + m, __ATOMIC_RELAXED,
                                                     __HIP_MEMORY_SCOPE_AGENT);
                d[m] = __uint_as_float(w);
                rdy = rdy && ((w >> 31) == 0u);
            }
            if (__all(rdy)) break;
            __builtin_amdgcn_s_sleep(1);
        }
        *(float4*)(&drow[wave * NN + lane * 8])     = *(float4*)&d[0];
        *(float4*)(&drow[wave * NN + lane * 8 + 4]) = *(float4*)&d[4];
        const int lj = slbl[j];
        if (lane == 0) pcnt[wave] = 0;          // per-wave DS ops are in-order
        #pragma unroll
        for (int m = 0; m < 8; ++m) {
            const int k = lane * 8 + m;
            if (k != j && lb[m] == lj) {
                const int ix = atomicAdd(&pcnt[wave], 1);
                plist[wave * 128 + ix] = (unsigned short)k;
            }
        }
        float vmaxl = 0.f;                      // max over negatives (fallback)
        #pragma unroll
        for (int m = 0; m < 8; ++m) if (lb[m] != lj) vmaxl = fmaxf(vmaxl, d[m]);
        #pragma unroll
        for (int o = 32; o > 0; o >>= 1) vmaxl = fmaxf(vmaxl, __shfl_xor(vmaxl, o, 64));
        const int np = pcnt[wave];
        bc += (unsigned)np;
        for (int p = 0; p < np; ++p) {
            const int a = plist[wave * 128 + p];
            const float dpa = drow[wave * NN + a];
            float vm = 1e30f;                   // min negative strictly beyond dpa
            #pragma unroll
            for (int m = 0; m < 8; ++m) {
                const bool c = (lb[m] != lj) && (d[m] > dpa);
                vm = c ? fminf(vm, d[m]) : vm;
            }
            #pragma unroll
            for (int o = 32; o > 0; o >>= 1) vm = fminf(vm, __shfl_xor(vm, o, 64));
            const float neg = (vm < 1e29f) ? vm : vmaxl;
            const float term = MARGIN_F + dpa - neg;
            if (lane == 0 && term > 0.f) bl += term;
        }
    }
    if (lane == 0) { wl[wave] = bl; wc[wave] = (int)bc; }
    __syncthreads();
    if (tid == 0) {
        float L = 0.f; int C = 0;
        #pragma unroll
        for (int w = 0; w < 8; ++w) { L += wl[w]; C += wc[w]; }
        __hip_atomic_store((float*)&ctrl[bi], L, __ATOMIC_RELAXED,
                           __HIP_MEMORY_SCOPE_AGENT);                 // L >= 0
        __hip_atomic_store(&ctrl[16 + bi], C + 1, __ATOMIC_RELAXED,
                           __HIP_MEMORY_SCOPE_AGENT);                 // >= 1
        if (bi == 15) {                        // finalizer: poll all 16 slots
            float Ls = 0.f; int Cs = 0;
            for (int m = 0; m < 16; ++m) {
                unsigned wLu, wCu;
                do { wLu = __hip_atomic_load((unsigned*)&ctrl[m], __ATOMIC_RELAXED,
                                             __HIP_MEMORY_SCOPE_AGENT);
                } while (wLu >> 31);
                do { wCu = __hip_atomic_load((unsigned*)&ctrl[16 + m], __ATOMIC_RELAXED,
                                             __HIP_MEMORY_SCOPE_AGENT);
                } while (wCu >> 31);
                Ls += __uint_as_float(wLu);
                Cs += (int)wCu - 1;
            }
            out[0] = Ls / ((float)Cs + 1e-8f);
        }
    }
}

extern "C" void kernel_launch(void* const* d_in, const int* in_sizes, int n_in,
                              void* d_out, int out_size, void* d_ws, size_t ws_size,
                              hipStream_t stream) {
    (void)in_sizes; (void)n_in; (void)out_size; (void)ws_size;
    const int* labels = (const int*)d_in[0];
    const float* emb  = (const float*)d_in[1];
    char* ws = (char*)d_ws;
    float* Dm   = (float*)ws;                     // 1 MB (poisoned negative each call)
    int*   ctrl = (int*)(ws + (1u << 20));        // 32 ints (poisoned negative)

    k_all<<<136, 512, 0, stream>>>(labels, emb, Dm, ctrl, (float*)d_out);
}

// Round 11
// 77.438 us; speedup vs baseline: 1.0765x; 1.0765x over previous
//
#include <hip/hip_runtime.h>
#include <math.h>

// TripletLoss semi-hard mining, N=512, D=512, C=64.
// v11: v9 (best, 76.7us) + coalesced symmetric Dm stores.
//   k_dist: 136 upper-triangle 32x32 tiles, 512 thr. Stage 64 fp32 rows ->
//     bf16 hi/lo in LDS, norms; Gram via 3 MFMAs/k-step (hi*hi+hi*lo+lo*hi),
//     K split across wave halves, combined via LDS scratch.
//     Epilogue (NEW): each lane's f32x4 = 4 consecutive ROWS x 1 col; by
//     symmetry store it as ONE dwordx4 at the transposed position
//     Dm[col][row0..3] (lower mirror), and after the per-wave 16x17 LDS
//     transpose store ONE dwordx4 for the upper tile. 8 scattered dword
//     stores/lane -> 2 coalesced dwordx4 (diag blocks: bitwise-equal dups).
//   k_mine: per-row mining (v4-verified, unchanged x5) + done-counter final.
// For each ordered positive pair (j,a):
//   neg = min{ d[j][k] : lbl[k]!=lbl[j], d[j][k] > d[j][a] }
//         else max{ d[j][k] : lbl[k]!=lbl[j] } (0 if none)
//   loss += max(0, MARGIN + d[j][a] - neg);  out = loss / (numpos + 1e-8)

#define NN 512
#define MARGIN_F 0.2f
#define LK 528                    // LDS row stride in shorts

typedef __attribute__((ext_vector_type(8))) short bf16x8;
typedef __attribute__((ext_vector_type(4))) float f32x4;

__device__ __forceinline__ unsigned short f2bf(float x){
    unsigned u = __float_as_uint(x);
    return (unsigned short)((u + 0x7FFFu + ((u >> 16) & 1u)) >> 16);   // RNE
}
__device__ __forceinline__ float bf2f(unsigned short h){
    return __uint_as_float(((unsigned)h) << 16);
}

// LDS byte offsets
#define SH_OFF   0                 // 4*32*528*2 = 135168
#define SNI_OFF  135168            // 32 f32
#define SNJ_OFF  135296            // 32 f32
#define SCR_OFF  135424            // 4*64*16 = 4096 (K-half partials)
#define TRP_OFF  139520            // 4 * 16*17*4 = 4352 (per-wave transpose)
#define SM_BYTES 143872

// ---------------- k_dist: symmetric distance tiles ----------------
__global__ __launch_bounds__(512) void k_dist(
    const float* __restrict__ emb,
    float* __restrict__ Dm,
    int* __restrict__ ctrl)        // [0]=loss f32, [1]=cnt u32, [2]=done u32
{
    __shared__ __align__(16) char sm[SM_BYTES];
    short* sh  = (short*)(sm + SH_OFF);           // [4][32][LK] Ihi/Ilo/Jhi/Jlo
    float* snI = (float*)(sm + SNI_OFF);
    float* snJ = (float*)(sm + SNJ_OFF);
    f32x4* scr = (f32x4*)(sm + SCR_OFF);          // [4][64]
    float* trp = (float*)(sm + TRP_OFF);          // [4][16*17]

    const int tid  = threadIdx.x;
    const int wave = tid >> 6, lane = tid & 63;

    // triangle map: blockIdx.x in [0,136) -> (bi,bj), bi<=bj
    int t = blockIdx.x, bi = 0;
    #pragma unroll
    for (int r = 0; r < 16; ++r) {
        const int rowlen = 16 - r;
        if (t < rowlen) { bi = r; break; }
        t -= rowlen;
    }
    const int bj = bi + t;

    if (blockIdx.x == 0 && tid < 3) ctrl[tid] = 0;

    // ---- staging: 64 rows (32 I + 32 J) fp32 -> bf16 hi/lo + norms ----
    {
        const int row = tid >> 3;                 // 0..63
        const int s8  = tid & 7;
        const int isJ = row >> 5;                 // 0:I 1:J
        const int rl  = row & 31;
        const int grow = (isJ ? bj : bi) * 32 + rl;
        const int bhi = (isJ << 1), blo = bhi + 1;
        const float4* Ep = (const float4*)emb;    // 128 float4 per row
        float ss = 0.f;
        #pragma unroll
        for (int i = 0; i < 16; ++i) {
            const int c4 = s8 + (i << 3);         // 0..127
            const float4 v = Ep[(size_t)grow * 128 + c4];
            ss = fmaf(v.x, v.x, ss); ss = fmaf(v.y, v.y, ss);
            ss = fmaf(v.z, v.z, ss); ss = fmaf(v.w, v.w, ss);
            ushort4 h, l;
            h.x = f2bf(v.x); l.x = f2bf(v.x - bf2f(h.x));
            h.y = f2bf(v.y); l.y = f2bf(v.y - bf2f(h.y));
            h.z = f2bf(v.z); l.z = f2bf(v.z - bf2f(h.z));
            h.w = f2bf(v.w); l.w = f2bf(v.w - bf2f(h.w));
            *(ushort4*)(&sh[(bhi * 32 + rl) * LK + (c4 << 2)]) = h;
            *(ushort4*)(&sh[(blo * 32 + rl) * LK + (c4 << 2)]) = l;
        }
        ss += __shfl_xor(ss, 1, 64);
        ss += __shfl_xor(ss, 2, 64);
        ss += __shfl_xor(ss, 4, 64);
        if (s8 == 0) { if (isJ) snJ[rl] = ss; else snI[rl] = ss; }
    }
    __syncthreads();

    // ---- MFMA: quad = quadrant, khalf = K half ----
    const int quad = wave & 3, khalf = wave >> 2;
    const int rowb = (quad >> 1) << 4, colb = (quad & 1) << 4;
    const int fr = lane & 15;
    const int q4 = lane >> 4;                     // 0..3
    const int k0 = q4 << 3;
    f32x4 acc = {0.f, 0.f, 0.f, 0.f};
    #pragma unroll
    for (int t8 = 0; t8 < 8; ++t8) {
        const int k = k0 + (((khalf << 3) + t8) << 5);
        const bf16x8 ahi = *(const bf16x8*)(&sh[(0 * 32 + rowb + fr) * LK + k]);
        const bf16x8 alo = *(const bf16x8*)(&sh[(1 * 32 + rowb + fr) * LK + k]);
        const bf16x8 bhi = *(const bf16x8*)(&sh[(2 * 32 + colb + fr) * LK + k]);
        const bf16x8 blo = *(const bf16x8*)(&sh[(3 * 32 + colb + fr) * LK + k]);
        acc = __builtin_amdgcn_mfma_f32_16x16x32_bf16(ahi, bhi, acc, 0, 0, 0);
        acc = __builtin_amdgcn_mfma_f32_16x16x32_bf16(ahi, blo, acc, 0, 0, 0);
        acc = __builtin_amdgcn_mfma_f32_16x16x32_bf16(alo, bhi, acc, 0, 0, 0);
    }
    if (khalf == 1) scr[quad * 64 + lane] = acc;
    __syncthreads();
    if (khalf == 0) {
        const f32x4 other = scr[quad * 64 + lane];
        acc[0] += other[0]; acc[1] += other[1];
        acc[2] += other[2]; acc[3] += other[3];
        // C/D layout col=lane&15, row=(lane>>4)*4+reg (m89-verified):
        // this lane holds d(rows rl0..rl0+3, col colg) — 4 consecutive rows.
        const int colg = bj * 32 + colb + fr;
        const float sc = snJ[colb + fr];
        const int rl0 = rowb + (q4 << 2);
        float4 dv;
        dv.x = sqrtf(fmaxf(snI[rl0 + 0] + sc - 2.f * acc[0], 0.f));
        dv.y = sqrtf(fmaxf(snI[rl0 + 1] + sc - 2.f * acc[1], 0.f));
        dv.z = sqrtf(fmaxf(snI[rl0 + 2] + sc - 2.f * acc[2], 0.f));
        dv.w = sqrtf(fmaxf(snI[rl0 + 3] + sc - 2.f * acc[3], 0.f));
        // lower-mirror orientation, coalesced: Dm[colg][bi*32+rl0 .. +3] = dv
        // (valid because D is symmetric; diag blocks: bitwise-equal duplicate)
        *(float4*)(&Dm[(size_t)colg * NN + bi * 32 + rl0]) = dv;
        // upper tile via per-wave 16x17 LDS transpose (intra-wave, in-order)
        float* T = trp + quad * (16 * 17);        // T[col][row]
        T[fr * 17 + (q4 << 2) + 0] = dv.x;
        T[fr * 17 + (q4 << 2) + 1] = dv.y;
        T[fr * 17 + (q4 << 2) + 2] = dv.z;
        T[fr * 17 + (q4 << 2) + 3] = dv.w;
        float4 mv;                                // d(row=fr, cols 4q4..+3)
        mv.x = T[((q4 << 2) + 0) * 17 + fr];
        mv.y = T[((q4 << 2) + 1) * 17 + fr];
        mv.z = T[((q4 << 2) + 2) * 17 + fr];
        mv.w = T[((q4 << 2) + 3) * 17 + fr];
        *(float4*)(&Dm[(size_t)(bi * 32 + rowb + fr) * NN
                       + bj * 32 + colb + (q4 << 2)]) = mv;
    }
}

// ---------------- k_mine: mining + finalize (v4-verified) ----------------
__global__ __launch_bounds__(256) void k_mine(
    const int* __restrict__ labels,
    const float* __restrict__ Dm,
    float* __restrict__ accums,          // [0]=loss [1]=cnt(u32) [2]=done(u32)
    float* __restrict__ out,
    int nblocks)
{
    __shared__ int slbl[NN];
    __shared__ float drow[4][NN];
    __shared__ unsigned short plist[4][128];
    __shared__ int pcnt[4];

    const int tid = threadIdx.x, wave = tid >> 6, lane = tid & 63;
    const int j = blockIdx.x * 4 + wave;

    slbl[tid] = labels[tid];
    slbl[tid + 256] = labels[tid + 256];
    if (tid < 4) pcnt[tid] = 0;
    __syncthreads();

    // distance row j: 8 values per lane in registers + LDS copy for dpa lookups
    const float4* rp = (const float4*)(Dm + (size_t)j * NN);
    const float4 va = rp[lane * 2], vb = rp[lane * 2 + 1];
    *(float4*)(&drow[wave][lane * 8]) = va;
    *(float4*)(&drow[wave][lane * 8 + 4]) = vb;
    float d[8] = {va.x, va.y, va.z, va.w, vb.x, vb.y, vb.z, vb.w};
    const int lj = slbl[j];
    int lb[8];
    #pragma unroll
    for (int m = 0; m < 8; ++m) lb[m] = slbl[lane * 8 + m];

    // positive list (wave-local LDS; in-order per-wave DS ops)
    #pragma unroll
    for (int m = 0; m < 8; ++m){
        const int k = lane * 8 + m;
        if (k != j && lb[m] == lj){
            const int ix = atomicAdd(&pcnt[wave], 1);
            plist[wave][ix] = (unsigned short)k;
        }
    }
    // max over negatives: dpa-independent, reduce once per row
    float vmaxl = 0.f;
    #pragma unroll
    for (int m = 0; m < 8; ++m) if (lb[m] != lj) vmaxl = fmaxf(vmaxl, d[m]);
    #pragma unroll
    for (int o = 32; o > 0; o >>= 1) vmaxl = fmaxf(vmaxl, __shfl_xor(vmaxl, o, 64));

    const int np = pcnt[wave];
    float wloss = 0.f;
    for (int p = 0; p < np; ++p){
        const int a = plist[wave][p];
        const float dpa = drow[wave][a];
        float vm = 1e30f;   // min negative strictly farther than dpa
        #pragma unroll
        for (int m = 0; m < 8; ++m){
            const bool cnd = (lb[m] != lj) && (d[m] > dpa);
            vm = cnd ? fminf(vm, d[m]) : vm;
        }
        #pragma unroll
        for (int o = 32; o > 0; o >>= 1) vm = fminf(vm, __shfl_xor(vm, o, 64));
        const float neg = (vm < 1e29f) ? vm : vmaxl;
        const float term = MARGIN_F + dpa - neg;
        if (lane == 0 && term > 0.f) wloss += term;
    }
    if (lane == 0){
        if (wloss != 0.f) atomicAdd(&accums[0], wloss);
        if (np) atomicAdd((unsigned int*)&accums[1], (unsigned int)np);
    }
    __syncthreads();
    if (tid == 0){
        __threadfence();
        const unsigned old = atomicAdd((unsigned int*)&accums[2], 1u);
        if (old == (unsigned)(nblocks - 1)){
            const float L = atomicAdd(&accums[0], 0.f);
            const unsigned C = atomicAdd((unsigned int*)&accums[1], 0u);
            out[0] = L / ((float)C + 1e-8f);
        }
    }
}

extern "C" void kernel_launch(void* const* d_in, const int* in_sizes, int n_in,
                              void* d_out, int out_size, void* d_ws, size_t ws_size,
                              hipStream_t stream) {
    (void)in_sizes; (void)n_in; (void)out_size; (void)ws_size;
    const int* labels = (const int*)d_in[0];
    const float* emb  = (const float*)d_in[1];
    char* ws = (char*)d_ws;
    float* Dm   = (float*)ws;                     // 1 MB
    int*   ctrl = (int*)(ws + (1u << 20));        // 3 ints

    k_dist<<<136, 512, 0, stream>>>(emb, Dm, ctrl);
    k_mine<<<128, 256, 0, stream>>>(labels, Dm, (float*)ctrl, (float*)d_out, 128);
}